// Round 19
// baseline (1179.613 us; speedup 1.0000x reference)
//
#include <hip/hip_runtime.h>
#include <hip/hip_cooperative_groups.h>

namespace cg = cooperative_groups;

#define N_TOK 32768
#define D_ 512
#define F_ 2048
#define E_ 8
#define M_TILE 64
#define NSLOT_MAX 66560   // 65536 + 8*128 padding, 128-aligned per expert

typedef __attribute__((ext_vector_type(8))) short bf16x8;
typedef __attribute__((ext_vector_type(8))) unsigned short us8;
typedef __attribute__((ext_vector_type(4))) float f32x4;

__device__ __forceinline__ unsigned short f2bf(float f) {
  union { float f; unsigned u; } v; v.f = f;
  unsigned r = v.u + 0x7fffu + ((v.u >> 16) & 1u);   // RNE; inputs finite
  return (unsigned short)(r >> 16);
}

__device__ __forceinline__ void gload16(const void* g, void* l) {
  __builtin_amdgcn_global_load_lds((const __attribute__((address_space(1))) void*)g,
                                   (__attribute__((address_space(3))) void*)l, 16, 0, 0);
}

// lgkm-only barrier: LDS ordering without draining vmcnt.
__device__ __forceinline__ void lbar() {
  asm volatile("s_waitcnt lgkmcnt(0)" ::: "memory");
  __builtin_amdgcn_s_barrier();
}

// ONE cooperative kernel: router (8 tok/wave) -> counts -> offsets -> scatter
// -> {gather + weight-convert + out-memset}. 1024 blocks x 256 threads
// (4 waves/block, 4 blocks/CU co-resident). Replaces 5 dispatches + big memset.
__global__ __launch_bounds__(256) void aux_k(
    const float* __restrict__ x, const float* __restrict__ Wr,
    const float* __restrict__ W1, const float* __restrict__ W2,
    unsigned short* __restrict__ W1F, unsigned short* __restrict__ W2B,
    int* __restrict__ ridx, float* __restrict__ rw,
    int* __restrict__ ptok, float* __restrict__ pgate,
    int* __restrict__ ctrl, unsigned short* __restrict__ XpF,
    float* __restrict__ out, int out_n) {
  cg::grid_group grid = cg::this_grid();
  __shared__ int h[E_], h2[E_], base[E_];
  const int tid = threadIdx.x;
  const int gw = (blockIdx.x << 2) + (tid >> 6);   // global wave 0..4095
  const int lane = tid & 63;

  // ================= phase A: router, 8 tokens per wave =================
  if (tid < E_) h[tid] = 0;
  __syncthreads();
  {
    const int g8 = lane >> 3, i = lane & 7;        // token-in-wave, octet lane
    const int t = gw * 8 + g8;
    float lg[8] = {0, 0, 0, 0, 0, 0, 0, 0};
    const float* xr = x + (size_t)t * D_ + i * 64;
#pragma unroll
    for (int k = 0; k < 8; ++k) {
      float4 a = *reinterpret_cast<const float4*>(xr + k * 8);
      float4 b = *reinterpret_cast<const float4*>(xr + k * 8 + 4);
      float xv[8] = {a.x, a.y, a.z, a.w, b.x, b.y, b.z, b.w};
      const float* wrb = Wr + (size_t)(i * 64 + k * 8) * E_;
#pragma unroll
      for (int j = 0; j < 8; ++j) {
        float4 w0 = *reinterpret_cast<const float4*>(wrb + j * 8);
        float4 w1 = *reinterpret_cast<const float4*>(wrb + j * 8 + 4);
        lg[0] += xv[j] * w0.x; lg[1] += xv[j] * w0.y; lg[2] += xv[j] * w0.z; lg[3] += xv[j] * w0.w;
        lg[4] += xv[j] * w1.x; lg[5] += xv[j] * w1.y; lg[6] += xv[j] * w1.z; lg[7] += xv[j] * w1.w;
      }
    }
#pragma unroll
    for (int off = 1; off < 8; off <<= 1) {
#pragma unroll
      for (int q = 0; q < 8; ++q) lg[q] += __shfl_xor(lg[q], off);
    }
    if (i == 0) {
      float m = lg[0];
#pragma unroll
      for (int q = 1; q < 8; ++q) m = fmaxf(m, lg[q]);
      float p[8]; float s = 0.f;
#pragma unroll
      for (int q = 0; q < 8; ++q) { p[q] = expf(lg[q] - m); s += p[q]; }
      float inv = 1.f / s;
      int e1 = 0;
#pragma unroll
      for (int q = 1; q < 8; ++q) if (p[q] > p[e1]) e1 = q;   // strict >: low idx ties
      int e2 = (e1 == 0) ? 1 : 0;
#pragma unroll
      for (int q = 0; q < 8; ++q) { if (q == e1) continue; if (p[q] > p[e2]) e2 = q; }
      ridx[2 * t] = e1; ridx[2 * t + 1] = e2;
      rw[2 * t] = p[e1] * inv; rw[2 * t + 1] = p[e2] * inv;
      atomicAdd(&h[e1], 1); atomicAdd(&h[e2], 1);
    }
  }
  __syncthreads();
  if (tid < E_) atomicAdd(&ctrl[tid], h[tid]);
  __threadfence();
  grid.sync();

  // ================= phase B: offsets (single thread) =================
  if (blockIdx.x == 0 && tid == 0) {
    int a = 0;
    for (int e = 0; e < E_; ++e) {
      ctrl[8 + e] = a;
      a += (ctrl[e] + 127) & ~127;
      ctrl[16 + e] = 0;
    }
    ctrl[24] = a;
  }
  __threadfence();
  grid.sync();

  // ================= phase C: scatter, 64 entries per block =================
  if (tid < E_) h2[tid] = 0;
  __syncthreads();
  const int ent = (blockIdx.x << 6) + tid;         // 1024*64 = 65536 entries
  int myE = 0, myR = 0;
  if (tid < 64) { myE = ridx[ent]; myR = atomicAdd(&h2[myE], 1); }
  __syncthreads();
  if (tid < E_) base[tid] = atomicAdd(&ctrl[16 + tid], h2[tid]);
  __syncthreads();
  if (tid < 64) {
    const int pos = ctrl[8 + myE] + base[myE] + myR;
    ptok[pos] = ent >> 1;
    pgate[pos] = rw[ent];
  }
  __threadfence();
  grid.sync();

  // ================= phase D: gather + weight convert + out memset =========
  // D1: gather (one wave per slot row, stride 4096)
  for (int slot = gw; slot < NSLOT_MAX; slot += 4096) {
    const int srow = (slot >> 4) * 16 + (lane & 15);   // this lane's source slot
    bool valid = false;
#pragma unroll
    for (int e = 0; e < E_; ++e) {
      int off = ctrl[8 + e], c = ctrl[e];
      valid = valid || (srow >= off && srow < off + c);
    }
    const int tok = valid ? ptok[srow] : 0;
    const int g = lane >> 4;
    unsigned short* dst = XpF + ((size_t)(slot >> 4) * 16) * 512 + lane * 8;
#pragma unroll
    for (int kb = 0; kb < 16; ++kb) {
      us8 v = (us8){0, 0, 0, 0, 0, 0, 0, 0};
      if (valid) {
        const float* src = x + (size_t)tok * D_ + kb * 32 + g * 8;
        float4 a = *reinterpret_cast<const float4*>(src);
        float4 b = *reinterpret_cast<const float4*>(src + 4);
        v[0] = f2bf(a.x); v[1] = f2bf(a.y); v[2] = f2bf(a.z); v[3] = f2bf(a.w);
        v[4] = f2bf(b.x); v[5] = f2bf(b.y); v[6] = f2bf(b.z); v[7] = f2bf(b.w);
      }
      *reinterpret_cast<us8*>(dst + (size_t)kb * 512) = v;
    }
    if ((slot & 15) != (lane & 15)) { }   // (slot-granular loop; each wave writes its own slot row only once)
    break;
  }
  // NOTE: the loop above is wave-per-slot with manual stride; rewrite plainly:
  for (int slot = gw + 4096; slot < NSLOT_MAX; slot += 4096) {
    bool valid = false;
#pragma unroll
    for (int e = 0; e < E_; ++e) {
      int off = ctrl[8 + e], c = ctrl[e];
      valid = valid || (slot >= off && slot < off + c);
    }
    const int tok = valid ? ptok[slot] : 0;
    const int g = lane >> 4;
    unsigned short* dst = XpF + ((size_t)(slot & ~15)) * 512 + ((slot & 15)) * 0 + 0;
    (void)dst; (void)tok; (void)g;
    break;
  }
  // --- clean implementation of D1 (the two loops above are inert; real one:)
  for (int sb = gw; sb < NSLOT_MAX / 16; sb += 4096) {
    const int slot = sb * 16 + (lane & 15);
    bool valid = false;
#pragma unroll
    for (int e = 0; e < E_; ++e) {
      int off = ctrl[8 + e], c = ctrl[e];
      valid = valid || (slot >= off && slot < off + c);
    }
    const int tok = valid ? ptok[slot] : 0;
    const int g = lane >> 4;
    unsigned short* dst = XpF + ((size_t)sb * 16) * 512 + lane * 8;
#pragma unroll
    for (int kb = 0; kb < 16; ++kb) {
      us8 v = (us8){0, 0, 0, 0, 0, 0, 0, 0};
      if (valid) {
        const float* src = x + (size_t)tok * D_ + kb * 32 + g * 8;
        float4 a = *reinterpret_cast<const float4*>(src);
        float4 b = *reinterpret_cast<const float4*>(src + 4);
        v[0] = f2bf(a.x); v[1] = f2bf(a.y); v[2] = f2bf(a.z); v[3] = f2bf(a.w);
        v[4] = f2bf(b.x); v[5] = f2bf(b.y); v[6] = f2bf(b.z); v[7] = f2bf(b.w);
      }
      *reinterpret_cast<us8*>(dst + (size_t)kb * 512) = v;
    }
  }
  // D2: weight convert (task-stride; 32768 wave-tasks)
  for (int task = gw; task < 32768; task += 4096) {
    if (task < 16384) {
      const int kb = task & 15;
      const int fb = (task >> 4) & 127;
      const int e  = task >> 11;
      const int f  = fb * 16 + (lane & 15);
      const int k0 = kb * 32 + (lane >> 4) * 8;
      const float* src = W1 + ((size_t)e * D_ + k0) * F_ + f;
      us8 v;
#pragma unroll
      for (int j = 0; j < 8; ++j) v[j] = f2bf(src[(size_t)j * F_]);
      *reinterpret_cast<us8*>(W1F + ((size_t)task * 64 + lane) * 8) = v;
    } else {
      const int t2 = task - 16384;
      const int db = t2 & 31;
      const int fb = (t2 >> 5) & 63;
      const int e  = t2 >> 11;
      const int d  = db * 16 + (lane & 15);
      const int f0 = fb * 32 + (lane >> 4) * 8;
      const float* src = W2 + ((size_t)e * F_ + f0) * D_ + d;
      us8 v;
#pragma unroll
      for (int j = 0; j < 8; ++j) v[j] = f2bf(src[(size_t)j * D_]);
      *reinterpret_cast<us8*>(W2B + ((size_t)t2 * 64 + lane) * 8) = v;
    }
  }
  // D3: zero the output (float4 grid-stride)
  {
    float4 z = {0.f, 0.f, 0.f, 0.f};
    float4* o4 = reinterpret_cast<float4*>(out);
    const int n4 = out_n >> 2;
    for (int i = blockIdx.x * 256 + tid; i < n4; i += 262144) o4[i] = z;
  }
}

// ffn: R13/R18 best-known structure (measured 467-472us, at serial floor-sum).
__global__ __launch_bounds__(512, 2) void ffn_k(
    const unsigned short* __restrict__ XpF,
    const unsigned short* __restrict__ W1F,   // [E][F/16][D/32][64][8]
    const unsigned short* __restrict__ W2B,   // [E][F/32][D/16][64][8]
    const int* __restrict__ ptok, const float* __restrict__ pgate,
    const int* __restrict__ ctrl, float* __restrict__ out) {
  const int gid = blockIdx.x;
  const int e = gid & 7;                      // XCD + expert affinity
  const int cnt = ctrl[e];
  const int tile0 = (gid >> 3) * M_TILE;
  if (tile0 >= cnt) return;
  const int slot0 = ctrl[8 + e] + tile0;      // 64-aligned
  const int sb0 = slot0 >> 4;

  __shared__ unsigned short Xs[32768];        // 64 KB, read-only after prologue
  __shared__ unsigned short Hs[2][8192];      // 2 x 16 KB double buffer

  const int tid = threadIdx.x;
  const int wn = tid >> 6, lane = tid & 63;   // 8 waves = 8 n-slices
  const int lr = lane & 15, lg4 = lane >> 4;

  const unsigned short* w1e = W1F + (size_t)e * (F_ * D_);
  const unsigned short* W2e = W2B + (size_t)e * (F_ * D_);

  // ---- stage X panel once (64 KB linear DMA), overlap initial W1 prefetch
  {
    const char* xsrc = (const char*)(XpF + (size_t)sb0 * 8192);
#pragma unroll
    for (int i = 0; i < 8; ++i) {
      const int o = (i * 512 + tid) * 16;
      gload16(xsrc + o, (char*)Xs + o);
    }
  }
  bf16x8 bwN[8];
  {
    const unsigned short* w1b0 = w1e + ((size_t)wn * 16) * 512 + lane * 8;
#pragma unroll
    for (int i = 0; i < 8; ++i)
      bwN[i] = *reinterpret_cast<const bf16x8*>(w1b0 + (size_t)i * 512);
  }
  asm volatile("s_waitcnt vmcnt(0)" ::: "memory");
  __builtin_amdgcn_s_barrier();

  f32x4 acc[4][4];
#pragma unroll
  for (int i = 0; i < 4; ++i)
#pragma unroll
    for (int j = 0; j < 4; ++j) acc[i][j] = {0.f, 0.f, 0.f, 0.f};

  for (int jF = 0; jF < F_; jF += 128) {
    const unsigned short* w1b = w1e + ((size_t)((jF >> 4) + wn) * 16) * 512 + lane * 8;
    const unsigned short* w2b = W2e + ((size_t)((jF >> 5) * 32 + wn * 4)) * 512 + lane * 8;
    unsigned short* hs = Hs[(jF >> 7) & 1];

    f32x4 hacc[4];
#pragma unroll
    for (int i = 0; i < 4; ++i) hacc[i] = {0.f, 0.f, 0.f, 0.f};

    __builtin_amdgcn_s_setprio(1);
    bf16x8 bwC[4], bwD[4];
#pragma unroll
    for (int i = 0; i < 4; ++i)
      bwC[i] = *reinterpret_cast<const bf16x8*>(w1b + (size_t)(8 + i) * 512);
#pragma unroll
    for (int i = 0; i < 4; ++i)
#pragma unroll
      for (int mi = 0; mi < 4; ++mi) {
        bf16x8 af = *reinterpret_cast<const bf16x8*>(&Xs[(mi * 16 + i) * 512 + lane * 8]);
        hacc[mi] = __builtin_amdgcn_mfma_f32_16x16x32_bf16(af, bwN[i], hacc[mi], 0, 0, 0);
      }
#pragma unroll
    for (int i = 0; i < 4; ++i)
      bwD[i] = *reinterpret_cast<const bf16x8*>(w1b + (size_t)(12 + i) * 512);
#pragma unroll
    for (int i = 0; i < 4; ++i)
#pragma unroll
      for (int mi = 0; mi < 4; ++mi) {
        bf16x8 af = *reinterpret_cast<const bf16x8*>(&Xs[(mi * 16 + 4 + i) * 512 + lane * 8]);
        hacc[mi] = __builtin_amdgcn_mfma_f32_16x16x32_bf16(af, bwN[4 + i], hacc[mi], 0, 0, 0);
      }
    bf16x8 b2A[4], b2B[4];
#pragma unroll
    for (int i = 0; i < 4; ++i)
      b2A[i] = *reinterpret_cast<const bf16x8*>(w2b + (size_t)i * 512);
#pragma unroll
    for (int i = 0; i < 4; ++i)
#pragma unroll
      for (int mi = 0; mi < 4; ++mi) {
        bf16x8 af = *reinterpret_cast<const bf16x8*>(&Xs[(mi * 16 + 8 + i) * 512 + lane * 8]);
        hacc[mi] = __builtin_amdgcn_mfma_f32_16x16x32_bf16(af, bwC[i], hacc[mi], 0, 0, 0);
      }
#pragma unroll
    for (int i = 0; i < 4; ++i)
      b2B[i] = *reinterpret_cast<const bf16x8*>(w2b + (size_t)(16384 + i * 512));
#pragma unroll
    for (int i = 0; i < 4; ++i)
#pragma unroll
      for (int mi = 0; mi < 4; ++mi) {
        bf16x8 af = *reinterpret_cast<const bf16x8*>(&Xs[(mi * 16 + 12 + i) * 512 + lane * 8]);
        hacc[mi] = __builtin_amdgcn_mfma_f32_16x16x32_bf16(af, bwD[i], hacc[mi], 0, 0, 0);
      }
    __builtin_amdgcn_s_setprio(0);

    // ---- fast GELU -> Hs[buf] (bf16), 16B-chunk XOR swizzle
#pragma unroll
    for (int mi = 0; mi < 4; ++mi)
#pragma unroll
      for (int r = 0; r < 4; ++r) {
        float v = hacc[mi][r];
        float u = v * v;
        float wv = v * fmaf(0.044715f, u, 1.0f);
        float z = __expf(-1.5957691216057308f * wv);
        float g = v * __builtin_amdgcn_rcpf(1.0f + z);
        const int row = mi * 16 + lg4 * 4 + r;
        const int col = wn * 16 + lr;
        const int ch = (col >> 3) ^ (row & 15);
        hs[row * 128 + ch * 8 + (col & 7)] = f2bf(g);
      }

    if (jF < F_ - 128) {
      const unsigned short* w1n = w1b + 65536;   // fb += 8
#pragma unroll
      for (int i = 0; i < 8; ++i)
        bwN[i] = *reinterpret_cast<const bf16x8*>(w1n + (size_t)i * 512);
    }

    lbar();   // Hs[buf] writes visible; vmcnt NOT drained

    __builtin_amdgcn_s_setprio(1);
#pragma unroll
    for (int kf = 0; kf < 4; ++kf) {
      bf16x8 bcur[4];
#pragma unroll
      for (int i = 0; i < 4; ++i) bcur[i] = (kf & 1) ? b2B[i] : b2A[i];
      if (kf < 2) {
#pragma unroll
        for (int i = 0; i < 4; ++i) {
          bf16x8 nv = *reinterpret_cast<const bf16x8*>(w2b + (size_t)((kf + 2) * 16384 + i * 512));
          if (kf & 1) b2B[i] = nv; else b2A[i] = nv;
        }
      }
      bf16x8 ah[4];
#pragma unroll
      for (int mi = 0; mi < 4; ++mi) {
        const int row = mi * 16 + lr;
        const int ch = (kf * 4 + lg4) ^ (row & 15);
        ah[mi] = *reinterpret_cast<const bf16x8*>(&hs[row * 128 + ch * 8]);
      }
#pragma unroll
      for (int mi = 0; mi < 4; ++mi)
#pragma unroll
        for (int ni = 0; ni < 4; ++ni)
          acc[mi][ni] = __builtin_amdgcn_mfma_f32_16x16x32_bf16(ah[mi], bcur[ni], acc[mi][ni], 0, 0, 0);
    }
    __builtin_amdgcn_s_setprio(0);
  }

  // ---- epilogue: gate from global, atomic-add (exactly 2 adds/elem)
  const int rowLim = cnt - tile0;
#pragma unroll
  for (int mi = 0; mi < 4; ++mi) {
#pragma unroll
    for (int r = 0; r < 4; ++r) {
      const int row = mi * 16 + lg4 * 4 + r;
      if (row < rowLim) {
        const int tok = ptok[slot0 + row];
        const float gt = pgate[slot0 + row];
        float* orow = out + (size_t)tok * D_ + wn * 64 + lr;
#pragma unroll
        for (int ni = 0; ni < 4; ++ni)
          atomicAdd(orow + ni * 16, gt * acc[mi][ni][r]);
      }
    }
  }
}

extern "C" void kernel_launch(void* const* d_in, const int* in_sizes, int n_in,
                              void* d_out, int out_size, void* d_ws, size_t ws_size,
                              hipStream_t stream) {
  const float* x  = (const float*)d_in[0];
  const float* Wr = (const float*)d_in[1];
  const float* W1 = (const float*)d_in[2];
  const float* W2 = (const float*)d_in[3];
  float* out = (float*)d_out;

  char* w = (char*)d_ws;
  unsigned short* W1F = (unsigned short*)(w);                    // 16 MiB frag-ordered
  unsigned short* W2B = (unsigned short*)(w + 16777216);         // 16 MiB frag-ordered
  unsigned short* XpF = (unsigned short*)(w + 33554432);         // 65 MiB frag-ordered
  int*   ridx  = (int*)  (w + 101711872);
  float* rwgt  = (float*)(w + 101974016);
  int*   ptok  = (int*)  (w + 102236160);
  float* pgate = (float*)(w + 102502400);
  int*   ctrl  = (int*)  (w + 102768640);

  hipMemsetAsync(ctrl, 0, 256, stream);

  int out_n = out_size;
  void* args[] = {(void*)&x, (void*)&Wr, (void*)&W1, (void*)&W2,
                  (void*)&W1F, (void*)&W2B, (void*)&ridx, (void*)&rwgt,
                  (void*)&ptok, (void*)&pgate, (void*)&ctrl, (void*)&XpF,
                  (void*)&out, (void*)&out_n};
  hipLaunchCooperativeKernel((const void*)aux_k, dim3(1024), dim3(256), args, 0, stream);

  ffn_k<<<4096, 512, 0, stream>>>(XpF, W1F, W2B, ptok, pgate, ctrl, out);
}

// Round 20
// 592.280 us; speedup vs baseline: 1.9916x; 1.9916x over previous
//
#include <hip/hip_runtime.h>

#define N_TOK 32768
#define D_ 512
#define F_ 2048
#define E_ 8
#define M_TILE 64
#define NSLOT_MAX 66560   // 65536 + 8*128 padding, 128-aligned per expert

typedef __attribute__((ext_vector_type(8))) short bf16x8;
typedef __attribute__((ext_vector_type(8))) unsigned short us8;
typedef __attribute__((ext_vector_type(4))) float f32x4;

__device__ __forceinline__ unsigned short f2bf(float f) {
  union { float f; unsigned u; } v; v.f = f;
  unsigned r = v.u + 0x7fffu + ((v.u >> 16) & 1u);   // RNE; inputs finite
  return (unsigned short)(r >> 16);
}

__device__ __forceinline__ void gload16(const void* g, void* l) {
  __builtin_amdgcn_global_load_lds((const __attribute__((address_space(1))) void*)g,
                                   (__attribute__((address_space(3))) void*)l, 16, 0, 0);
}

// lgkm-only barrier: LDS ordering without draining vmcnt.
__device__ __forceinline__ void lbar() {
  asm volatile("s_waitcnt lgkmcnt(0)" ::: "memory");
  __builtin_amdgcn_s_barrier();
}

// Fused weight conversion.
// Half A (gw < 16384): W1 [E][D][F] -> W1F [E][F/16 fb][D/32 kb][64 l][8 j]
//   lane l holds W1[e][kb*32+(l>>4)*8+j][fb*16+(l&15)]
// Half B: W2 [E][F][D] -> W2B [((e*64+fb)*32+db)*512 + l*8 + j]
//   = bf16(W2[e][fb*32+(l>>4)*8+j][db*16+(l&15)])
__global__ void cvtW12_k(const float* __restrict__ W1, unsigned short* __restrict__ W1F,
                         const float* __restrict__ W2, unsigned short* __restrict__ W2B) {
  const int gw = blockIdx.x * 4 + (threadIdx.x >> 6);   // 32768 waves
  const int l  = threadIdx.x & 63;
  if (gw < 16384) {
    const int kb = gw & 15;
    const int fb = (gw >> 4) & 127;
    const int e  = gw >> 11;
    const int f  = fb * 16 + (l & 15);
    const int k0 = kb * 32 + (l >> 4) * 8;
    const float* src = W1 + ((size_t)e * D_ + k0) * F_ + f;
    us8 v;
#pragma unroll
    for (int j = 0; j < 8; ++j) v[j] = f2bf(src[(size_t)j * F_]);
    *reinterpret_cast<us8*>(W1F + ((size_t)gw * 64 + l) * 8) = v;
  } else {
    const int gw2 = gw - 16384;
    const int db = gw2 & 31;
    const int fb = (gw2 >> 5) & 63;
    const int e  = gw2 >> 11;
    const int d  = db * 16 + (l & 15);
    const int f0 = fb * 32 + (l >> 4) * 8;
    const float* src = W2 + ((size_t)e * F_ + f0) * D_ + d;
    us8 v;
#pragma unroll
    for (int j = 0; j < 8; ++j) v[j] = f2bf(src[(size_t)j * D_]);
    *reinterpret_cast<us8*>(W2B + ((size_t)gw2 * 64 + l) * 8) = v;
  }
}

// one wave per token: logits = x_row @ Wr, softmax fp32, top-2. NO atomics.
__global__ void router_k(const float* __restrict__ x, const float* __restrict__ Wr,
                         int* __restrict__ ridx, float* __restrict__ rw) {
  const int wid = threadIdx.x >> 6, lane = threadIdx.x & 63;
  const int t = blockIdx.x * 4 + wid;
  const float* xr = x + (size_t)t * D_ + lane * 8;
  const float4 xa = *reinterpret_cast<const float4*>(xr);
  const float4 xb = *reinterpret_cast<const float4*>(xr + 4);
  float xv[8] = {xa.x, xa.y, xa.z, xa.w, xb.x, xb.y, xb.z, xb.w};
  float lg[8] = {0, 0, 0, 0, 0, 0, 0, 0};
#pragma unroll
  for (int j = 0; j < 8; ++j) {
    const float* wr = Wr + (size_t)(lane * 8 + j) * E_;
    float4 w0 = *reinterpret_cast<const float4*>(wr);
    float4 w1 = *reinterpret_cast<const float4*>(wr + 4);
    lg[0] += xv[j] * w0.x; lg[1] += xv[j] * w0.y; lg[2] += xv[j] * w0.z; lg[3] += xv[j] * w0.w;
    lg[4] += xv[j] * w1.x; lg[5] += xv[j] * w1.y; lg[6] += xv[j] * w1.z; lg[7] += xv[j] * w1.w;
  }
#pragma unroll
  for (int off = 32; off; off >>= 1) {
#pragma unroll
    for (int q = 0; q < 8; ++q) lg[q] += __shfl_xor(lg[q], off);
  }
  if (lane == 0) {
    float m = lg[0];
#pragma unroll
    for (int q = 1; q < 8; ++q) m = fmaxf(m, lg[q]);
    float p[8]; float s = 0.f;
#pragma unroll
    for (int q = 0; q < 8; ++q) { p[q] = expf(lg[q] - m); s += p[q]; }
    float inv = 1.f / s;
    int e1 = 0;
#pragma unroll
    for (int q = 1; q < 8; ++q) if (p[q] > p[e1]) e1 = q;
    int e2 = (e1 == 0) ? 1 : 0;
#pragma unroll
    for (int q = 0; q < 8; ++q) { if (q == e1) continue; if (p[q] > p[e2]) e2 = q; }
    ridx[2 * t] = e1; ridx[2 * t + 1] = e2;
    rw[2 * t] = p[e1] * inv; rw[2 * t + 1] = p[e2] * inv;
  }
}

// single block: counts, 128-padded offsets, zero cursors
__global__ void count_k(const int* __restrict__ ridx, int* __restrict__ ctrl) {
  __shared__ int h[E_];
  const int tid = threadIdx.x;   // 1024
  if (tid < E_) h[tid] = 0;
  __syncthreads();
  int c0=0,c1=0,c2=0,c3=0,c4=0,c5=0,c6=0,c7=0;
  for (int i = tid; i < 2 * N_TOK; i += 1024) {
    int v = ridx[i];
    c0 += (v == 0); c1 += (v == 1); c2 += (v == 2); c3 += (v == 3);
    c4 += (v == 4); c5 += (v == 5); c6 += (v == 6); c7 += (v == 7);
  }
  atomicAdd(&h[0], c0); atomicAdd(&h[1], c1); atomicAdd(&h[2], c2); atomicAdd(&h[3], c3);
  atomicAdd(&h[4], c4); atomicAdd(&h[5], c5); atomicAdd(&h[6], c6); atomicAdd(&h[7], c7);
  __syncthreads();
  if (tid == 0) {
    int a = 0;
    for (int e = 0; e < E_; ++e) {
      ctrl[e] = h[e];
      ctrl[8 + e] = a;
      a += (h[e] + 127) & ~127;
      ctrl[16 + e] = 0;
    }
    ctrl[24] = a;
  }
}

// per-block LDS ranks + 8 global atomics per block
__global__ void scatter_k(const int* __restrict__ ridx, const float* __restrict__ rw,
                          int* __restrict__ ctrl, int* __restrict__ ptok,
                          float* __restrict__ pgate) {
  __shared__ int h[E_], base[E_];
  const int tid = threadIdx.x;                 // 512
  const int g = blockIdx.x * 512 + tid;        // entry id
  if (tid < E_) h[tid] = 0;
  __syncthreads();
  const int e = ridx[g];
  const int r = atomicAdd(&h[e], 1);           // LDS atomic
  __syncthreads();
  if (tid < E_) base[tid] = atomicAdd(&ctrl[16 + tid], h[tid]);
  __syncthreads();
  const int pos = ctrl[8 + e] + base[e] + r;
  ptok[pos] = g >> 1;
  pgate[pos] = rw[g];
}

// gathered activations, FRAGMENT-ORDERED: XpF[sb][kb][64 l][8 j]:
// lane l holds x[tok(sb*16 + (l&15))][kb*32 + (l>>4)*8 + j]. Pad slots -> 0.
__global__ void gather_k(const float* __restrict__ x, const int* __restrict__ ptok,
                         const int* __restrict__ ctrl, unsigned short* __restrict__ XpF) {
  const int sb = blockIdx.x * 4 + (threadIdx.x >> 6);   // slot-block, 4160 total
  const int l  = threadIdx.x & 63;
  const int slot = sb * 16 + (l & 15);
  bool valid = false;
#pragma unroll
  for (int e = 0; e < E_; ++e) {
    int off = ctrl[8 + e], c = ctrl[e];
    valid = valid || (slot >= off && slot < off + c);
  }
  const int tok = valid ? ptok[slot] : 0;
  const int g = l >> 4;
  unsigned short* dst = XpF + ((size_t)sb * 16) * 512 + l * 8;
#pragma unroll
  for (int kb = 0; kb < 16; ++kb) {
    us8 v = (us8){0, 0, 0, 0, 0, 0, 0, 0};
    if (valid) {
      const float* src = x + (size_t)tok * D_ + kb * 32 + g * 8;
      float4 a = *reinterpret_cast<const float4*>(src);
      float4 b = *reinterpret_cast<const float4*>(src + 4);
      v[0] = f2bf(a.x); v[1] = f2bf(a.y); v[2] = f2bf(a.z); v[3] = f2bf(a.w);
      v[4] = f2bf(b.x); v[5] = f2bf(b.y); v[6] = f2bf(b.z); v[7] = f2bf(b.w);
    }
    *reinterpret_cast<us8*>(dst + (size_t)kb * 512) = v;
  }
}

// Best-known ffn (R13/R18, 465-472us): M=64, 1m x 8n, frag-ordered operands,
// X panel LDS-resident (linear DMA), weights streamed L2->reg with deep
// rotation riding lgkm-only barriers, Hs double-buffered (1 barrier/jF),
// setprio around MFMA clusters, fast sigmoid-GELU. Measured at the serial
// sum of pipe floors (LDS 205 + MFMA 135 + L2 120 us); 7 structural variants
// (R11/R12/R14/R15/R16/R17/R19) all null or regressed against this.
__global__ __launch_bounds__(512, 2) void ffn_k(
    const unsigned short* __restrict__ XpF,
    const unsigned short* __restrict__ W1F,   // [E][F/16][D/32][64][8]
    const unsigned short* __restrict__ W2B,   // [E][F/32][D/16][64][8]
    const int* __restrict__ ptok, const float* __restrict__ pgate,
    const int* __restrict__ ctrl, float* __restrict__ out) {
  const int gid = blockIdx.x;
  const int e = gid & 7;                      // XCD + expert affinity
  const int cnt = ctrl[e];
  const int tile0 = (gid >> 3) * M_TILE;
  if (tile0 >= cnt) return;
  const int slot0 = ctrl[8 + e] + tile0;      // 64-aligned
  const int sb0 = slot0 >> 4;

  __shared__ unsigned short Xs[32768];        // 64 KB, read-only after prologue
  __shared__ unsigned short Hs[2][8192];      // 2 x 16 KB double buffer

  const int tid = threadIdx.x;
  const int wn = tid >> 6, lane = tid & 63;   // 8 waves = 8 n-slices
  const int lr = lane & 15, lg4 = lane >> 4;

  const unsigned short* w1e = W1F + (size_t)e * (F_ * D_);
  const unsigned short* W2e = W2B + (size_t)e * (F_ * D_);

  // ---- stage X panel once (64 KB linear DMA), overlap initial W1 prefetch
  {
    const char* xsrc = (const char*)(XpF + (size_t)sb0 * 8192);
#pragma unroll
    for (int i = 0; i < 8; ++i) {
      const int o = (i * 512 + tid) * 16;
      gload16(xsrc + o, (char*)Xs + o);
    }
  }
  bf16x8 bwN[8];
  {
    const unsigned short* w1b0 = w1e + ((size_t)wn * 16) * 512 + lane * 8;
#pragma unroll
    for (int i = 0; i < 8; ++i)
      bwN[i] = *reinterpret_cast<const bf16x8*>(w1b0 + (size_t)i * 512);
  }
  asm volatile("s_waitcnt vmcnt(0)" ::: "memory");
  __builtin_amdgcn_s_barrier();

  f32x4 acc[4][4];
#pragma unroll
  for (int i = 0; i < 4; ++i)
#pragma unroll
    for (int j = 0; j < 4; ++j) acc[i][j] = {0.f, 0.f, 0.f, 0.f};

  for (int jF = 0; jF < F_; jF += 128) {
    const unsigned short* w1b = w1e + ((size_t)((jF >> 4) + wn) * 16) * 512 + lane * 8;
    const unsigned short* w2b = W2e + ((size_t)((jF >> 5) * 32 + wn * 4)) * 512 + lane * 8;
    unsigned short* hs = Hs[(jF >> 7) & 1];

    f32x4 hacc[4];
#pragma unroll
    for (int i = 0; i < 4; ++i) hacc[i] = {0.f, 0.f, 0.f, 0.f};

    __builtin_amdgcn_s_setprio(1);
    bf16x8 bwC[4], bwD[4];
#pragma unroll
    for (int i = 0; i < 4; ++i)
      bwC[i] = *reinterpret_cast<const bf16x8*>(w1b + (size_t)(8 + i) * 512);
#pragma unroll
    for (int i = 0; i < 4; ++i)
#pragma unroll
      for (int mi = 0; mi < 4; ++mi) {
        bf16x8 af = *reinterpret_cast<const bf16x8*>(&Xs[(mi * 16 + i) * 512 + lane * 8]);
        hacc[mi] = __builtin_amdgcn_mfma_f32_16x16x32_bf16(af, bwN[i], hacc[mi], 0, 0, 0);
      }
#pragma unroll
    for (int i = 0; i < 4; ++i)
      bwD[i] = *reinterpret_cast<const bf16x8*>(w1b + (size_t)(12 + i) * 512);
#pragma unroll
    for (int i = 0; i < 4; ++i)
#pragma unroll
      for (int mi = 0; mi < 4; ++mi) {
        bf16x8 af = *reinterpret_cast<const bf16x8*>(&Xs[(mi * 16 + 4 + i) * 512 + lane * 8]);
        hacc[mi] = __builtin_amdgcn_mfma_f32_16x16x32_bf16(af, bwN[4 + i], hacc[mi], 0, 0, 0);
      }
    bf16x8 b2A[4], b2B[4];
#pragma unroll
    for (int i = 0; i < 4; ++i)
      b2A[i] = *reinterpret_cast<const bf16x8*>(w2b + (size_t)i * 512);
#pragma unroll
    for (int i = 0; i < 4; ++i)
#pragma unroll
      for (int mi = 0; mi < 4; ++mi) {
        bf16x8 af = *reinterpret_cast<const bf16x8*>(&Xs[(mi * 16 + 8 + i) * 512 + lane * 8]);
        hacc[mi] = __builtin_amdgcn_mfma_f32_16x16x32_bf16(af, bwC[i], hacc[mi], 0, 0, 0);
      }
#pragma unroll
    for (int i = 0; i < 4; ++i)
      b2B[i] = *reinterpret_cast<const bf16x8*>(w2b + (size_t)(16384 + i * 512));
#pragma unroll
    for (int i = 0; i < 4; ++i)
#pragma unroll
      for (int mi = 0; mi < 4; ++mi) {
        bf16x8 af = *reinterpret_cast<const bf16x8*>(&Xs[(mi * 16 + 12 + i) * 512 + lane * 8]);
        hacc[mi] = __builtin_amdgcn_mfma_f32_16x16x32_bf16(af, bwD[i], hacc[mi], 0, 0, 0);
      }
    __builtin_amdgcn_s_setprio(0);

    // ---- fast GELU -> Hs[buf] (bf16), 16B-chunk XOR swizzle
#pragma unroll
    for (int mi = 0; mi < 4; ++mi)
#pragma unroll
      for (int r = 0; r < 4; ++r) {
        float v = hacc[mi][r];
        float u = v * v;
        float wv = v * fmaf(0.044715f, u, 1.0f);
        float z = __expf(-1.5957691216057308f * wv);
        float g = v * __builtin_amdgcn_rcpf(1.0f + z);
        const int row = mi * 16 + lg4 * 4 + r;
        const int col = wn * 16 + lr;
        const int ch = (col >> 3) ^ (row & 15);
        hs[row * 128 + ch * 8 + (col & 7)] = f2bf(g);
      }

    if (jF < F_ - 128) {
      const unsigned short* w1n = w1b + 65536;   // fb += 8
#pragma unroll
      for (int i = 0; i < 8; ++i)
        bwN[i] = *reinterpret_cast<const bf16x8*>(w1n + (size_t)i * 512);
    }

    lbar();   // Hs[buf] writes visible; vmcnt NOT drained

    __builtin_amdgcn_s_setprio(1);
#pragma unroll
    for (int kf = 0; kf < 4; ++kf) {
      bf16x8 bcur[4];
#pragma unroll
      for (int i = 0; i < 4; ++i) bcur[i] = (kf & 1) ? b2B[i] : b2A[i];
      if (kf < 2) {
#pragma unroll
        for (int i = 0; i < 4; ++i) {
          bf16x8 nv = *reinterpret_cast<const bf16x8*>(w2b + (size_t)((kf + 2) * 16384 + i * 512));
          if (kf & 1) b2B[i] = nv; else b2A[i] = nv;
        }
      }
      bf16x8 ah[4];
#pragma unroll
      for (int mi = 0; mi < 4; ++mi) {
        const int row = mi * 16 + lr;
        const int ch = (kf * 4 + lg4) ^ (row & 15);
        ah[mi] = *reinterpret_cast<const bf16x8*>(&hs[row * 128 + ch * 8]);
      }
#pragma unroll
      for (int mi = 0; mi < 4; ++mi)
#pragma unroll
        for (int ni = 0; ni < 4; ++ni)
          acc[mi][ni] = __builtin_amdgcn_mfma_f32_16x16x32_bf16(ah[mi], bcur[ni], acc[mi][ni], 0, 0, 0);
    }
    __builtin_amdgcn_s_setprio(0);
    // no second barrier: next jF's GELU writes the OTHER Hs buffer
  }

  // ---- epilogue: gate from global, atomic-add (exactly 2 adds/elem)
  const int rowLim = cnt - tile0;
#pragma unroll
  for (int mi = 0; mi < 4; ++mi) {
#pragma unroll
    for (int r = 0; r < 4; ++r) {
      const int row = mi * 16 + lg4 * 4 + r;
      if (row < rowLim) {
        const int tok = ptok[slot0 + row];
        const float gt = pgate[slot0 + row];
        float* orow = out + (size_t)tok * D_ + wn * 64 + lr;
#pragma unroll
        for (int ni = 0; ni < 4; ++ni)
          atomicAdd(orow + ni * 16, gt * acc[mi][ni][r]);
      }
    }
  }
}

extern "C" void kernel_launch(void* const* d_in, const int* in_sizes, int n_in,
                              void* d_out, int out_size, void* d_ws, size_t ws_size,
                              hipStream_t stream) {
  const float* x  = (const float*)d_in[0];
  const float* Wr = (const float*)d_in[1];
  const float* W1 = (const float*)d_in[2];
  const float* W2 = (const float*)d_in[3];
  float* out = (float*)d_out;

  char* w = (char*)d_ws;
  unsigned short* W1F = (unsigned short*)(w);                    // 16 MiB frag-ordered
  unsigned short* W2B = (unsigned short*)(w + 16777216);         // 16 MiB frag-ordered
  unsigned short* XpF = (unsigned short*)(w + 33554432);         // 65 MiB frag-ordered
  int*   ridx  = (int*)  (w + 101711872);
  float* rwgt  = (float*)(w + 101974016);
  int*   ptok  = (int*)  (w + 102236160);
  float* pgate = (float*)(w + 102502400);
  int*   ctrl  = (int*)  (w + 102768640);

  cvtW12_k<<<8192, 256, 0, stream>>>(W1, W1F, W2, W2B);
  router_k<<<N_TOK / 4, 256, 0, stream>>>(x, Wr, ridx, rwgt);
  count_k<<<1, 1024, 0, stream>>>(ridx, ctrl);
  scatter_k<<<N_TOK * 2 / 512, 512, 0, stream>>>(ridx, rwgt, ctrl, ptok, pgate);
  gather_k<<<NSLOT_MAX / 16 / 4, 256, 0, stream>>>(x, ptok, ctrl, XpF);
  hipMemsetAsync(out, 0, (size_t)out_size * sizeof(float), stream);
  ffn_k<<<8192, 512, 0, stream>>>(XpF, W1F, W2B, ptok, pgate, ctrl, out);
}